// Round 11
// baseline (751.178 us; speedup 1.0000x reference)
//
#include <hip/hip_runtime.h>
#include <hip/hip_bf16.h>

typedef __bf16 bf16;
typedef __attribute__((ext_vector_type(8))) __bf16 v8bf;
typedef __attribute__((ext_vector_type(4))) float f32x4;
typedef __attribute__((ext_vector_type(16))) float f32x16;

#define HH 55
#define WW 128
#define HWP 7040
#define BHW 14080
#define QS 0.08838834764831845f
#define LOG2E 1.4426950408889634f

__device__ __forceinline__ void g2l16(const bf16* g, bf16* l){
  __builtin_amdgcn_global_load_lds(
      (const __attribute__((address_space(1))) void*)g,
      (__attribute__((address_space(3))) void*)l, 16, 0, 0);
}

// ===========================================================================
// Weight prepack tables. Bp[t][co][ci] bf16 (B^T layout), zero-padded.
// Q half of w_qk pre-scaled by QS. Dst-major enumeration (coalesced writes).
// Entries 8/11: r*h-slice (K=128) of wq1/wq2; 17/18: x-slice (K=384,off 128).
// ===========================================================================
#define NCV 19
__device__ const int PK_srcCS[NCV]  = {324,256,128,256,128,128,512,512,512,512,512,512,128,128,256,256,98,512,512};
__device__ const int PK_csv[NCV]    = {324,256,128,256,128,128,512,512,128,512,512,128,128,128,256,256,98,384,384};
__device__ const int PK_srcOff[NCV] = {0,0,0,0,0,0,0,0,0,0,0,0,0,0,0,0,0,128,128};
__device__ const int PK_wsrc[NCV]   = {0,1,2,3,4,5,6,7,8,9,10,11,12,13,14,15,16,8,11};
__device__ const int PK_Kc[NCV]     = {384,256,128,256,128,128,512,512,128,512,512,128,128,128,256,256,128,384,384};
__device__ const int PK_ntap[NCV]   = {1,9,9,9,1,1,5,5,5,5,5,5,9,9,9,1,1,5,5};
__device__ const int PK_Ctot[NCV]   = {256,256,128,128,256,128,256,256,128,256,256,128,512,512,128,640,128,128,128};
__device__ const int PK_coB[NCV]    = {0,0,0,0,0,0,0,128,0,0,128,0,0,256,0,0,0,0,0};
__device__ const int PK_dst[NCV]    = {0,98304,688128,835584,1130496,1163264,1179648,1179648,
  1835008,2162688,2162688,2818048,3145728,3145728,3735552,4030464,4194304,1916928,2899968};
__device__ const int PKD_cum[NCV+1] = {0,98304,540672,614400,904704,937472,953856,
  1281536,1609216,1691136,2018816,2346496,2428416,2723328,3018240,3022848,3170304,
  3186688,3432448,3678208};
__device__ const int PKD_Co[NCV]    = {256,192,64,126,256,128,128,128,128,128,128,128,256,256,2,576,128,128,128};

__device__ const int PB_off[15]={0,256,512,640,1152,1280,1408,1536,1664,1792,1920,2176,2432,2560,3200};
__device__ const int PB_cnt[15]={256,192,64,126,128,128,128,128,128,128,256,256,2,576,128};

struct W17 { const float* w[17]; };
struct B15 { const float* b[15]; };

// ===========================================================================
// init_k: one launch for {pack_w (dst-major), transp2, transp_f(corr),
// tflow, im2col, pack_b} — all mutually independent.
// ===========================================================================
struct XP {
  W17 wp; B15 bp;
  const float *net, *inp, *corr, *flow;
  bf16 *Bp; float *bias;
  bf16 *hx; float *hcur; bf16 *corr_cl; bf16 *im2c;
};

__global__ __launch_bounds__(256) void init_k(XP X){
  __shared__ float T[64][65];
  int bid = blockIdx.x;
  const int t = threadIdx.x;
  if (bid < 14368){
    int idx = bid*256 + t;                 // 3678208 = 14368*256
    int c = 0;
    while (idx >= PKD_cum[c+1]) ++c;
    int local = idx - PKD_cum[c];
    if (c == 16){
      int co = local >> 7, k = local & 127;
      if (k < 98)
        X.Bp[PK_dst[16] + co*128 + k] = (bf16)X.wp.w[16][co*98 + (k&1)*49 + (k>>1)];
      return;
    }
    int Kc = PK_Kc[c];
    int CKc = PKD_Co[c]*Kc;
    int tap = local / CKc;
    int rem = local - tap*CKc;
    int co = rem / Kc;
    int ci = rem - co*Kc;
    if (ci < PK_csv[c]){
      float v = X.wp.w[PK_wsrc[c]][(co*PK_srcCS[c] + PK_srcOff[c] + ci)*PK_ntap[c] + tap];
      if (c == 4 && co < 128) v *= QS;     // Q half pre-scaled
      X.Bp[PK_dst[c] + (tap*PK_Ctot[c] + PK_coB[c] + co)*Kc + ci] = (bf16)v;
    }
    return;
  }
  bid -= 14368;
  if (bid < 880){                          // transp2: net/inp -> hx + hcur
    int pt = bid%110, ct = (bid/110)&3, b = bid/440;
    const float* src = (ct < 2) ? X.net : X.inp;
    int c0s = (ct & 1)*64;
    int cbase = (ct < 2) ? 0 : 128;
    int p0 = pt*64;
    int pj = t & 63, cr4 = t >> 6;
#pragma unroll
    for (int i=0;i<16;++i)
      T[cr4 + i*4][pj] = src[((size_t)b*128 + c0s + cr4 + i*4)*HWP + p0 + pj];
    __syncthreads();
    int cj = t & 63, pr4 = t >> 6;
#pragma unroll
    for (int i=0;i<16;++i){
      int pp = p0 + pr4 + i*4;
      float v = T[cj][pr4 + i*4];
      X.hx[((size_t)(b*HWP+pp))*512 + cbase + c0s + cj] = (bf16)v;
      if (ct < 2) X.hcur[((size_t)(b*HWP+pp))*128 + c0s + cj] = v;
    }
    return;
  }
  bid -= 880;
  if (bid < 1320){                         // transp_f: corr -> corr_cl (384 pad)
    int pt = bid%110, ct = (bid/110)%6, b = bid/660;
    int p0 = pt*64, c0s = ct*64;
    int pj = t & 63, cr4 = t >> 6;
#pragma unroll
    for (int i=0;i<16;++i){
      int c = c0s + cr4 + i*4;
      float v = 0.f;
      if (c < 324) v = X.corr[((size_t)b*324 + c)*HWP + p0 + pj];
      T[cr4 + i*4][pj] = v;
    }
    __syncthreads();
    int cj = t & 63, pr4 = t >> 6;
#pragma unroll
    for (int i=0;i<16;++i){
      int pp = p0 + pr4 + i*4;
      int cc = c0s + cj;
      X.corr_cl[((size_t)(b*HWP+pp))*384 + cc] = (bf16)T[cj][pr4 + i*4];
    }
    return;
  }
  bid -= 1320;
  if (bid < 110){                          // tflow: flow -> hx[382:384)
    int i = bid*256 + t;                   // BHW*2
    int c = i & 1, p = i >> 1;
    int b = p / HWP, pix = p - b*HWP;
    X.hx[(size_t)p*512 + 382 + c] = (bf16)X.flow[(b*2+c)*HWP + pix];
    return;
  }
  bid -= 110;
  if (bid < 7040){                         // im2col: flow 7x7 -> im2c
    int i = bid*256 + t;                   // BHW*128
    int k = i & 127, p = i >> 7;
    int b = p / HWP, pix = p - b*HWP, y = pix >> 7, x = pix & 127;
    float v = 0.f;
    if (k < 98){
      int tap = k >> 1, c2 = k & 1, kh = tap/7, kw = tap - 7*(tap/7);
      int yy = y + kh - 3, xx = x + kw - 3;
      if ((unsigned)yy < 55u && (unsigned)xx < 128u) v = X.flow[(b*2+c2)*HWP + yy*128 + xx];
    }
    X.im2c[i] = (bf16)v;
    return;
  }
  // pack_b (last block)
  for (int e=0;e<15;++e)
    for (int o=t; o<PB_cnt[e]; o+=256)
      X.bias[PB_off[e]+o] = X.bp.b[e][o];
}

// ===========================================================================
// merge_k: enc3 staging (f32 ch-major, atomic-accumulated) -> relu -> bf16
// into hx[256:382). Channels 126/127 (tflow) preserved via RMW on the last
// 8-chunk. LDS transpose for coalesced reads + 16B hx stores.
// ===========================================================================
__global__ __launch_bounds__(256) void merge_k(
    const float* __restrict__ stag, bf16* __restrict__ hx)
{
  __shared__ float T[128][65];
  const int Mt = blockIdx.x;            // 0..219
  const int bimg = Mt/110;
  const int rem = Mt - bimg*110;
  const int pixloc0 = (rem>>1)*128 + ((rem & 1) << 6);
  const int t = threadIdx.x;
#pragma unroll
  for (int it=0; it<32; ++it){
    int idx = t + it*256;               // 8192 = 128ch x 64px
    int ch = idx >> 6, px = idx & 63;
    T[ch][px] = stag[((size_t)bimg*128 + ch)*HWP + pixloc0 + px];
  }
  __syncthreads();
  const int px = t >> 2, seg = t & 3;
  const size_t hbase = ((size_t)bimg*HWP + pixloc0 + px)*512 + 256;
#pragma unroll
  for (int k=0;k<4;++k){
    int c0 = seg*32 + k*8;
    v8bf o;
    if (c0 == 120){
      o = *(const v8bf*)(hx + hbase + 120);     // keep ch126/127 (tflow)
#pragma unroll
      for (int e=0;e<6;++e) o[e] = (bf16)fmaxf(T[120+e][px], 0.f);
    } else {
#pragma unroll
      for (int e=0;e<8;++e) o[e] = (bf16)fmaxf(T[c0+e][px], 0.f);
    }
    *(v8bf*)(hx + hbase + c0) = o;
  }
}

// ===========================================================================
// Implicit-GEMM conv: M64 x N128, BK=64, 4 waves 2x2. Triple-param launch.
// tapSplit tiles: nt selects a tap-range (tOff = nt*ntapN) with shared N
// range; partials atomically accumulated (outmode 6). Epilogue outmodes:
// 0 bf16 pix-major; 2 f32 ch-major; 5 bf16 ch-major (Vt); 6 f32 ch-major
// atomicAdd (tap-split heads); 1/3/4 scalar (GRU fusion; auxQ adds q
// x-part before activation).
// ===========================================================================
struct GP {
  const bf16* A; const bf16* A2;
  const bf16* Bp; const float* bias;
  void* outp; const float* auxZ; float* auxH; float* auxN; const float* auxQ;
  int Astride, A2stride, Asplit;
  int outCtot, outC0, Nvalid, Kc, CtotPad, tapcode, act, outmode, ntiles, ntOff;
  int ntapN, tapSplit;
  float scale;
};

__global__ __launch_bounds__(256) void gemm_conv(GP ga, GP gb, GP gc, const bf16* __restrict__ zp)
{
  const int Mt = blockIdx.x;            // 0..219
  int nt = blockIdx.y;
  GP g;
  if (nt < ga.ntiles){ g = ga; }
  else if (nt < ga.ntiles + gb.ntiles){ g = gb; nt -= ga.ntiles; }
  else { g = gc; nt -= ga.ntiles + gb.ntiles; }
  int tOff = 0;
  if (g.tapSplit){ tOff = nt * g.ntapN; nt = 0; }
  const bf16* A        = g.A;
  const bf16* A2       = g.A2;
  const bf16* Bp       = g.Bp;
  const float* bias    = g.bias;
  void* outp           = g.outp;
  const float* auxZ    = g.auxZ;
  float* auxH          = g.auxH;
  float* auxN          = g.auxN;
  const float* auxQ    = g.auxQ;
  const int Astride    = g.Astride;
  const int A2stride   = g.A2stride;
  const int Asplit     = g.Asplit;
  const int outCtot    = g.outCtot;
  const int outC0      = g.outC0;
  const int Nvalid     = g.Nvalid;
  const int Kc         = g.Kc;
  const int CtotPad    = g.CtotPad;
  const int tapcode    = g.tapcode;
  const int act        = g.act;
  const int outmode    = g.outmode;
  const int ntOff      = g.ntOff;
  const float scale    = g.scale;

  const int bimg = Mt/110;
  const int rem = Mt - bimg*110;
  const int yy0 = rem >> 1;
  const int xh  = (rem & 1) << 6;
  const int tid = threadIdx.x;
  const int lane = tid & 63, wave = tid >> 6;
  const int wm = wave >> 1, wn = wave & 1;
  const int lr = lane & 15, lq2 = lane >> 4;

  __shared__ __align__(16) bf16 Al[2][4096];   // [buf][64 rows x 64 elems]
  __shared__ __align__(16) bf16 Bl[2][8192];   // [buf][128 rows x 64 elems]

  f32x4 acc[2][4];
#pragma unroll
  for (int m=0;m<2;++m)
#pragma unroll
    for (int n=0;n<4;++n) acc[m][n] = (f32x4){0.f,0.f,0.f,0.f};

  const int ntap = g.ntapN ? g.ntapN : ((tapcode==0) ? 1 : (tapcode==1 ? 9 : 5));
  const int nsteps = ntap*(Kc>>6);

  const int srow = tid >> 3;            // 0..31
  const int sc   = tid & 7;             // chunk 0..7

#define STAGE(BUF, T, KC) { \
    int TT = (T) + tOff; \
    int ddy, ddx; \
    if (tapcode==0){ ddy=0; ddx=0; } \
    else if (tapcode==1){ ddy=TT/3-1; ddx=TT-3*(TT/3)-1; } \
    else if (tapcode==2){ ddy=0; ddx=TT-2; } \
    else { ddy=TT-2; ddx=0; } \
    int ysrc = yy0 + ddy; \
    bool yok = (unsigned)ysrc < 55u; \
    const bf16* Abase; int Astr; \
    if ((KC) < Asplit){ Astr = A2stride; \
      Abase = A2 + (size_t)((bimg*55+ysrc)*128)*Astr + (KC); } \
    else { Astr = Astride; \
      Abase = A + (size_t)((bimg*55+ysrc)*128)*Astr + (KC); } \
    _Pragma("unroll") \
    for (int is=0; is<2; ++is){ \
      int r = is*32 + srow; \
      int cc = sc ^ (r&7); \
      int gx = xh + r + ddx; \
      const bf16* srcp = (yok && (unsigned)gx < 128u) ? \
          (Abase + (size_t)gx*Astr + cc*8) : (zp + cc*8); \
      g2l16(srcp, &Al[BUF][is*2048 + wave*512]); \
    } \
    const bf16* Bt = Bp + (size_t)(TT*CtotPad + (nt+ntOff)*128)*Kc + (KC); \
    _Pragma("unroll") \
    for (int is=0; is<4; ++is){ \
      int r = is*32 + srow; \
      int cc = sc ^ (r&7); \
      g2l16(Bt + (size_t)r*Kc + cc*8, &Bl[BUF][is*2048 + wave*512]); \
    } }

  STAGE(0, 0, 0);
  __syncthreads();

  int tcur = 0, kcc = 0;
  for (int si=0; si<nsteps; ++si){
    int kn = kcc + 64, tn = tcur;
    if (kn == Kc){ kn = 0; tn = tcur + 1; }
    if (si + 1 < nsteps){ STAGE((si+1)&1, tn, kn); }
    __builtin_amdgcn_sched_barrier(0);
    kcc = kn; tcur = tn;
    const bf16* Ac = Al[si&1];
    const bf16* Bc = Bl[si&1];
#pragma unroll
    for (int kk=0; kk<2; ++kk){
      v8bf af[2], bfr[4];
#pragma unroll
      for (int m=0;m<2;++m){
        int row = wm*32 + m*16 + lr;
        af[m] = *(const v8bf*)(Ac + row*64 + (((kk*4+lq2) ^ (row&7))<<3));
      }
#pragma unroll
      for (int n=0;n<4;++n){
        int row = wn*64 + n*16 + lr;
        bfr[n] = *(const v8bf*)(Bc + row*64 + (((kk*4+lq2) ^ (row&7))<<3));
      }
#pragma unroll
      for (int m=0;m<2;++m)
#pragma unroll
        for (int n=0;n<4;++n)
          acc[m][n] = __builtin_amdgcn_mfma_f32_16x16x32_bf16(af[m], bfr[n], acc[m][n], 0,0,0);
    }
    __syncthreads();
  }
#undef STAGE

  const size_t pixbase = (size_t)(bimg*55 + yy0)*128 + xh;
  if (outmode == 0){
    // bf16 pix-major: LDS transpose (XOR-chunk swizzle) -> uint4 stores.
    bf16* Ost = (bf16*)Al;              // 64 x 128 bf16 = 16KB
#pragma unroll
    for (int nn=0; nn<4; ++nn){
      int colL = wn*64 + nn*16 + lr;
      float bvl = bias[(nt+ntOff)*128 + colL];
#pragma unroll
      for (int m=0;m<2;++m){
        int rowx = wm*32 + m*16 + lq2*4;
        f32x4 v = acc[m][nn];
#pragma unroll
        for (int r=0;r<4;++r){
          float vv = v[r] + bvl;
          if (act==1)      vv = fmaxf(vv, 0.f);
          else if (act==2) vv = 1.f/(1.f+__expf(-vv));
          else if (act==3) vv = tanhf(vv);
          vv *= scale;
          int row = rowx + r;
          int pch = (colL>>3) ^ (row & 7);
          Ost[row*128 + (pch<<3) + (colL&7)] = (bf16)vv;
        }
      }
    }
    __syncthreads();
    {
      int rowl = tid >> 2, seg = tid & 3;
      size_t p = pixbase + rowl;
      bf16* dstp = (bf16*)outp + p*outCtot + outC0 + (nt+ntOff)*128 + seg*32;
      const bf16* srcr = Ost + rowl*128;
      int cb = (nt+ntOff)*128 + seg*32;
#pragma unroll
      for (int k2=0;k2<4;++k2){
        int pch = (seg*4 + k2) ^ (rowl & 7);
        int cog = cb + k2*8;
        if (cog + 8 <= Nvalid)
          *(uint4*)(dstp + k2*8) = *(const uint4*)(srcr + (pch<<3));
        else if (cog < Nvalid){
          const bf16* s8 = srcr + (pch<<3);
          for (int e=0; e<Nvalid-cog; ++e) dstp[k2*8+e] = s8[e];
        }
      }
    }
  } else if (outmode == 2 || outmode == 6){
    // f32 channel-major: LDS [ch][row] -> 16B stores (2) or atomicAdd (6).
    float* Ost2 = (float*)Bl;           // 128 ch x 64 row f32 = 32KB
#pragma unroll
    for (int nn=0; nn<4; ++nn){
      int chL = wn*64 + nn*16 + lr;
      float bvl = (outmode==6 && tOff!=0) ? 0.f : bias[(nt+ntOff)*128 + chL];
#pragma unroll
      for (int m=0;m<2;++m){
        int rowx = wm*32 + m*16 + lq2*4;
        f32x4 v = acc[m][nn];
#pragma unroll
        for (int r=0;r<4;++r){
          float vv = v[r] + bvl;
          if (act==1)      vv = fmaxf(vv, 0.f);
          else if (act==2) vv = 1.f/(1.f+__expf(-vv));
          else if (act==3) vv = tanhf(vv);
          Ost2[chL*64 + rowx + r] = vv*scale;
        }
      }
    }
    __syncthreads();
    {
      int ch = tid >> 1, half = tid & 1;
      int cog = (nt+ntOff)*128 + ch;
      if (cog < Nvalid){
        float* dstp = (float*)outp + ((size_t)bimg*outCtot + outC0 + cog)*HWP
                    + yy0*128 + xh + half*32;
        const float* srcr = Ost2 + ch*64 + half*32;
        if (outmode == 2){
#pragma unroll
          for (int k2=0;k2<8;++k2)
            *(uint4*)(dstp + k2*4) = *(const uint4*)(srcr + k2*4);
        } else {
#pragma unroll
          for (int e=0;e<32;++e)
            atomicAdd(dstp + e, srcr[e]);
        }
      }
    }
  } else if (outmode == 5){
    // bf16 channel-major (Vt direct): LDS [ch][72pad] -> 16B stores along pix.
    bf16* Ost3 = (bf16*)Bl;             // 128 ch x 72 bf16 = 18.4KB (pad->align)
#pragma unroll
    for (int nn=0; nn<4; ++nn){
      int chL = wn*64 + nn*16 + lr;
      float bvl = bias[(nt+ntOff)*128 + chL];
#pragma unroll
      for (int m=0;m<2;++m){
        int rowx = wm*32 + m*16 + lq2*4;
        f32x4 v = acc[m][nn];
#pragma unroll
        for (int r=0;r<4;++r)
          Ost3[chL*72 + rowx + r] = (bf16)(v[r] + bvl);
      }
    }
    __syncthreads();
    {
      int ch = tid >> 1, half = tid & 1;
      bf16* dstp = (bf16*)outp + ((size_t)bimg*outCtot + outC0 + ch)*HWP
                 + yy0*128 + xh + half*32;
      const bf16* srcr = Ost3 + ch*72 + half*32;
#pragma unroll
      for (int k2=0;k2<4;++k2)
        *(uint4*)(dstp + k2*8) = *(const uint4*)(srcr + k2*8);
    }
  } else {
#pragma unroll
    for (int nn=0; nn<4; ++nn){
      int cog = (nt+ntOff)*128 + wn*64 + nn*16 + lr;
      float bvl = bias[cog];
      bool cok = cog < Nvalid;
#pragma unroll
      for (int m=0;m<2;++m){
        int rowx = wm*32 + m*16 + lq2*4;
        f32x4 v = acc[m][nn];
#pragma unroll
        for (int r=0;r<4;++r){
          int prow = rowx + r;
          size_t p = pixbase + prow;
          float vv = v[r] + bvl;
          if (outmode==4 && auxQ) vv += auxQ[p*128 + cog];
          if (act==1)      vv = fmaxf(vv, 0.f);
          else if (act==2) vv = 1.f/(1.f+__expf(-vv));
          else if (act==3) vv = tanhf(vv);
          vv *= scale;
          if (cok){
            if (outmode==1) ((float*)outp)[p*outCtot + outC0 + cog] = vv;
            else if (outmode==3){               // r-gate: rhb = sigmoid(.)*hcur
              int c = cog & 127;
              ((bf16*)outp)[p*128 + c] = (bf16)(vv * auxH[p*128 + c]);
            } else {                            // outmode==4: GRU update
              int c = cog;
              float z  = auxZ[p*128 + c];
              float h0 = auxH[p*128 + c];
              float hn = (1.f - z)*h0 + z*vv;
              auxH[p*128 + c] = hn;
              ((bf16*)outp)[p*512 + c] = (bf16)hn;
              if (auxN){
                int pixloc = (int)(p - (size_t)bimg*HWP);
                auxN[((size_t)bimg*128 + c)*HWP + pixloc] = hn;
              }
            }
          }
        }
      }
    }
  }
}

// ===========================================================================
// MFMA flash attention. r7 in-loop body (empirical best ~84us): single
// 8-deep QK chain, serial fmax, serial den, T12 cvt_pk+permlane pack,
// vectorized RMW epilogue. In-loop reorders measured harmful (r4/r8).
// ===========================================================================
__global__ __launch_bounds__(256,1) void attn_k(
    const bf16* __restrict__ QK, const bf16* __restrict__ Vt,
    bf16* __restrict__ hx,
    const float* __restrict__ gammap, const float* __restrict__ wprelup)
{
  __shared__ __align__(16) float SM[16640];
  const int tid = threadIdx.x;
  const int wv = tid >> 6, lane = tid & 63;
  const int lq = lane & 31, hi = lane >> 5;
  const int blk = blockIdx.x;
  const int qt = blk % 12;
  const int n  = (blk/12) % 21;
  const int b  = blk / 252;
  const int hs = n/7, wd = n - 7*hs;
  const int y0 = (hs-1)*19, x0 = (wd-1)*19;
  const int rylo = max(0, y0), ryhi = min(54, y0+56);
  const int rxlo = max(0, x0), rxhi = min(127, x0+56);
  const int rxA  = rxlo & ~7;
  const int s = qt*32 + lq;
  const int sy = s/19, sx = s - sy*19;
  const int qy = y0 + 19 + sy, qx = x0 + 19 + sx;
  const int qpix = (b*55 + min(qy,54))*128 + min(qx,127);
  const float a = wprelup[0]*0.02f;
  const float qyf = (float)qy;

  bf16* Kl = (bf16*)SM + wv*8192;
  bf16* Vl = Kl + 4096;

  v8bf qf[8];
#pragma unroll
  for (int ks=0; ks<8; ++ks)
    qf[ks] = *(const v8bf*)(QK + (size_t)qpix*256 + ks*16 + hi*8);

  float fx0[16], fx1[16];
  unsigned msk0 = 0, msk1 = 0;
  {
    float dxq0 = (float)(rxA - qx);
    int xl0 = rxlo - rxA, xm0 = rxhi - rxA;
#pragma unroll
    for (int r=0;r<16;++r){
      int Ri = (r&3) + 8*(r>>2) + 4*hi;
      float dxv = fabsf(dxq0 + (float)Ri) - 38.f;
      fx0[r] = fmaxf(1.f - fmaxf(dxv, a*dxv), 0.f);
      if (Ri >= xl0 && Ri <= xm0) msk0 |= 1u<<r;
      float dxv1 = fabsf(dxq0 + 32.f + (float)Ri) - 38.f;
      fx1[r] = fmaxf(1.f - fmaxf(dxv1, a*dxv1), 0.f);
      int Ri1 = Ri + 32;
      if (Ri1 >= xl0 && Ri1 <= xm0) msk1 |= 1u<<r;
    }
  }

  f32x16 acc[4];
#pragma unroll
  for (int nf=0; nf<4; ++nf)
#pragma unroll
    for (int r=0;r<16;++r) acc[nf][r] = 0.f;
  float m2 = -40.f, den = 0.f;

  const int nry = (ryhi - rylo - wv)/4 + 1;   // >= 9
  const int nit = nry*2;

#define ISSUE_K(RY, RX) { int pixK = (b*55+(RY))*128 + (RX); \
  _Pragma("unroll") \
  for (int i=0;i<8;++i){ \
    int key = i*4 + (lane>>4); int cs = (lane&15) ^ (key&7); \
    g2l16(QK + (size_t)(pixK+key)*256 + 128 + cs*8, Kl + i*512); } }
#define ISSUE_V(RY, RX) { \
  _Pragma("unroll") \
  for (int i=0;i<8;++i){ \
    int ch = i*16 + (lane>>2); int cs = (lane&3) ^ ((ch>>1)&3); \
    g2l16(Vt + (size_t)(b*128+ch)*HWP + (RY)*128 + (RX) + cs*8, Vl + i*512); } }

  ISSUE_K(rylo + wv, rxA);

  for (int it=0; it<nit; ++it){
    const int ry  = rylo + wv + (it>>1)*4;
    const int tpar = it & 1;
    asm volatile("s_waitcnt lgkmcnt(0)" ::: "memory");
    __builtin_amdgcn_sched_barrier(0);
    asm volatile("s_waitcnt vmcnt(0)" ::: "memory");
    __builtin_amdgcn_sched_barrier(0);
    ISSUE_V(ry, rxA + tpar*32);
    __builtin_amdgcn_sched_barrier(0);

    f32x16 Cs;
#pragma unroll
    for (int r=0;r<16;++r) Cs[r] = 0.f;
#pragma unroll
    for (int ks=0; ks<8; ++ks){
      v8bf kf = *(const v8bf*)(Kl + lq*128 + (((ks*2+hi) ^ (lq&7))<<3));
      Cs = __builtin_amdgcn_mfma_f32_32x32x16_bf16(kf, qf[ks], Cs, 0,0,0);
    }
    float pr[16];
    {
      float dyv = fabsf((float)ry - qyf) - 38.f;
      float fy = fmaxf(1.f - fmaxf(dyv, a*dyv), 0.f);
      float fyk = fy * LOG2E;
      unsigned mk = tpar ? msk1 : msk0;
      float l2v[16]; float tmax = -1e30f;
#pragma unroll
      for (int r=0;r<16;++r){
        float fx = tpar ? fx1[r] : fx0[r];
        float lv = fyk * fx * Cs[r];
        lv = ((mk>>r)&1u) ? lv : -1e30f;
        l2v[r] = lv;
        tmax = fmaxf(tmax, lv);
      }
      tmax = fmaxf(tmax, __shfl_xor(tmax, 32));
      if (__any(tmax > m2 + 11.f)){
        float m2n = fmaxf(m2, tmax);
        float sc = exp2f(m2 - m2n);
        den *= sc;
#pragma unroll
        for (int r=0;r<16;++r){
          float scr = __shfl(sc, (r&3) + 8*(r>>2) + 4*hi);
          acc[0][r]*=scr; acc[1][r]*=scr; acc[2][r]*=scr; acc[3][r]*=scr;
        }
        m2 = m2n;
      }
#pragma unroll
      for (int r=0;r<16;++r){
        pr[r] = exp2f(l2v[r] - m2);
        den += pr[r];
      }
    }
    asm volatile("s_waitcnt lgkmcnt(0)" ::: "memory");
    __builtin_amdgcn_sched_barrier(0);
    asm volatile("s_waitcnt vmcnt(0)" ::: "memory");
    __builtin_amdgcn_sched_barrier(0);
    if (it + 1 < nit){
      int ryn = rylo + wv + ((it+1)>>1)*4;
      ISSUE_K(ryn, rxA + ((it+1)&1)*32);
      __builtin_amdgcn_sched_barrier(0);
    }
    // T12 pack: 8 cvt_pk + 4 permlane32_swap -> pa0/pa1 directly.
    unsigned w0,w1,w2,w3,w4,w5,w6,w7;
    asm("v_cvt_pk_bf16_f32 %0, %1, %2" : "=v"(w0) : "v"(pr[0]),  "v"(pr[1]));
    asm("v_cvt_pk_bf16_f32 %0, %1, %2" : "=v"(w1) : "v"(pr[2]),  "v"(pr[3]));
    asm("v_cvt_pk_bf16_f32 %0, %1, %2" : "=v"(w2) : "v"(pr[4]),  "v"(pr[5]));
    asm("v_cvt_pk_bf16_f32 %0, %1, %2" : "=v"(w3) : "v"(pr[6]),  "v"(pr[7]));
    asm("v_cvt_pk_bf16_f32 %0, %1, %2" : "=v"(w4) : "v"(pr[8]),  "v"(pr[9]));
    asm("v_cvt_pk_bf16_f32 %0, %1, %2" : "=v"(w5) : "v"(pr[10]), "v"(pr[11]));
    asm("v_cvt_pk_bf16_f32 %0, %1, %2" : "=v"(w6) : "v"(pr[12]), "v"(pr[13]));
    asm("v_cvt_pk_bf16_f32 %0, %1, %2" : "=v"(w7) : "v"(pr[14]), "v"(pr[15]));
    asm("v_permlane32_swap_b32 %0, %1" : "+v"(w0), "+v"(w2));
    asm("v_permlane32_swap_b32 %0, %1" : "+v"(w1), "+v"(w3));
    asm("v_permlane32_swap_b32 %0, %1" : "+v"(w4), "+v"(w6));
    asm("v_permlane32_swap_b32 %0, %1" : "+v"(w5), "+v"(w7));
    union { unsigned u[4]; v8bf v; } U0, U1;
    U0.u[0]=w0; U0.u[1]=w1; U0.u[2]=w2; U0.u[3]=w3;
    U1.u[0]=w4; U1.u[1]=w5; U1.u[2]=w6; U1.u[3]=w7;
    v8bf pa0 = U0.v, pa1 = U1.v;
#pragma unroll
    for (int nf=0; nf<4; ++nf){
      int ch = nf*32 + lq;
      int sw = (lq>>1)&3;
      v8bf v0 = *(const v8bf*)(Vl + ch*32 + ((hi     ^ sw)<<3));
      v8bf v1 = *(const v8bf*)(Vl + ch*32 + (((2+hi) ^ sw)<<3));
      acc[nf] = __builtin_amdgcn_mfma_f32_32x32x16_bf16(pa0, v0, acc[nf], 0,0,0);
      acc[nf] = __builtin_amdgcn_mfma_f32_32x32x16_bf16(pa1, v1, acc[nf], 0,0,0);
    }
  }
#undef ISSUE_K
#undef ISSUE_V
  den += __shfl_xor(den, 32);

  float* Osh = SM;                    // [4][32][128]
  float* Msh = SM + 16384;
  float* Dsh = SM + 16512;
  __syncthreads();
#pragma unroll
  for (int nf=0; nf<4; ++nf)
#pragma unroll
    for (int r=0;r<16;++r)
      Osh[(wv*32 + (r&3) + 8*(r>>2) + 4*hi)*128 + nf*32 + lq] = acc[nf][r];
  if (hi == 0){ Msh[wv*32 + lq] = m2; Dsh[wv*32 + lq] = den; }
  __syncthreads();

  int q = tid >> 3, co = (tid & 7)*16;
  float m0 = Msh[q], m1 = Msh[32+q], mm2 = Msh[64+q], m3 = Msh[96+q];
  float M = fmaxf(fmaxf(m0,m1), fmaxf(mm2,m3));
  float s0 = exp2f(m0-M), s1 = exp2f(m1-M), s2 = exp2f(mm2-M), s3 = exp2f(m3-M);
  int ss = qt*32 + q;
  float dent = s0*Dsh[q] + s1*Dsh[32+q] + s2*Dsh[64+q] + s3*Dsh[96+q];
  int sy2 = ss/19, sx2 = ss - sy2*19;
  int qy2 = y0 + 19 + sy2, qx2 = x0 + 19 + sx2;
  if (ss < 361 && qy2 < 55 && qx2 < 128){
    size_t pix = (size_t)(b*55+qy2)*128 + qx2;
    float g = gammap[0] / dent;
    v8bf fm0 = *(const v8bf*)(hx + pix*512 + 256 + co);
    v8bf fm1 = *(const v8bf*)(hx + pix*512 + 256 + co + 8);
    v8bf o0, o1;
#pragma unroll
    for (int c=0;c<8;++c){
      float oa = s0*Osh[q*128+co+c] + s1*Osh[(32+q)*128+co+c]
               + s2*Osh[(64+q)*128+co+c] + s3*Osh[(96+q)*128+co+c];
      o0[c] = (bf16)((float)fm0[c] + oa*g);
      float ob = s0*Osh[q*128+co+8+c] + s1*Osh[(32+q)*128+co+8+c]
               + s2*Osh[(64+q)*128+co+8+c] + s3*Osh[(96+q)*128+co+8+c];
      o1[c] = (bf16)((float)fm1[c] + ob*g);
    }
    *(v8bf*)(hx + pix*512 + 384 + co)     = o0;
    *(v8bf*)(hx + pix*512 + 384 + co + 8) = o1;
  }
}

// ===========================================================================
static inline GP mkgp(const bf16* A, int Astride, const bf16* Bp, const float* bias,
                      void* outp, int outCtot, int outC0, int Nvalid, int Kc, int CtotPad,
                      int tapcode, int act, int outmode, float scale, int ntiles){
  GP g{};
  g.A=A; g.A2=A; g.Astride=Astride; g.A2stride=Astride; g.Asplit=0;
  g.Bp=Bp; g.bias=bias; g.outp=outp;
  g.auxZ=nullptr; g.auxH=nullptr; g.auxN=nullptr; g.auxQ=nullptr;
  g.outCtot=outCtot; g.outC0=outC0; g.Nvalid=Nvalid; g.Kc=Kc; g.CtotPad=CtotPad;
  g.tapcode=tapcode; g.act=act; g.outmode=outmode; g.ntiles=ntiles; g.ntOff=0;
  g.ntapN=0; g.tapSplit=0;
  g.scale=scale;
  return g;
}

extern "C" void kernel_launch(void* const* d_in, const int* in_sizes, int n_in,
                              void* d_out, int out_size, void* d_ws, size_t ws_size,
                              hipStream_t stream) {
  const float* net   = (const float*)d_in[0];
  const float* inp   = (const float*)d_in[1];
  const float* corr  = (const float*)d_in[2];
  const float* flow  = (const float*)d_in[3];
  const float* w_cor1=(const float*)d_in[4];  const float* b_cor1=(const float*)d_in[5];
  const float* w_cor2=(const float*)d_in[6];  const float* b_cor2=(const float*)d_in[7];
  const float* w_flo1=(const float*)d_in[8];  const float* b_flo1=(const float*)d_in[9];
  const float* w_flo2=(const float*)d_in[10]; const float* b_flo2=(const float*)d_in[11];
  const float* w_mo  =(const float*)d_in[12]; const float* b_mo  =(const float*)d_in[13];
  const float* w_qk  =(const float*)d_in[14];
  const float* w_v   =(const float*)d_in[15];
  const float* wz1=(const float*)d_in[16]; const float* bz1=(const float*)d_in[17];
  const float* wr1=(const float*)d_in[18]; const float* br1=(const float*)d_in[19];
  const float* wq1=(const float*)d_in[20]; const float* bq1=(const float*)d_in[21];
  const float* wz2=(const float*)d_in[22]; const float* bz2=(const float*)d_in[23];
  const float* wr2=(const float*)d_in[24]; const float* br2=(const float*)d_in[25];
  const float* wq2=(const float*)d_in[26]; const float* bq2=(const float*)d_in[27];
  const float* w_f1=(const float*)d_in[28]; const float* b_f1=(const float*)d_in[29];
  const float* w_f2=(const float*)d_in[30]; const float* b_f2=(const float*)d_in[31];
  const float* w_m1=(const float*)d_in[32]; const float* b_m1=(const float*)d_in[33];
  const float* w_m2=(const float*)d_in[34]; const float* b_m2=(const float*)d_in[35];
  const float* gamma  =(const float*)d_in[36];
  const float* w_prelu=(const float*)d_in[37];

  float* ws = (float*)d_ws;
  bf16* hx     = (bf16*)ws;                         // [0, 3604480)
  bf16* BPp    = (bf16*)(ws + 3604480);             // 4210688 bf16
  float* BIASp = ws + 5709824;                      // 3328 f32
  const bf16* zp = (const bf16*)(ws + 5713152);     // 256B zero page
  float* ZB0   = ws + 5713216;                      // 128 f32 zero bias
  const size_t S0 = 5713344;
  // encoder phase
  bf16* corr_cl = (bf16*)(ws + S0);                 // BHW*384 bf16
  bf16* fc1o    = (bf16*)(ws + S0 + 2703360);       // BHW*256 bf16
  float* fc1oF  = ws + S0 + 2703360;                // enc3 staging (same region)
  bf16* catB    = (bf16*)(ws + S0 + 4505600);       // BHW*256 bf16
  bf16* ff1o    = (bf16*)(ws + S0 + 6307840);       // BHW*128 bf16
  bf16* im2c    = (bf16*)(ws + S0 + 7208960);       // BHW*128 bf16
  float* hcur   = ws + S0 + 8110080;                // BHW*128 f32
  // attention phase overlays
  bf16* QKb    = (bf16*)(ws + S0);                  // 14144*256 bf16
  bf16* Vt     = (bf16*)(ws + S0 + 2711552);        // 2*128*7040 + pad
  // GRU phase overlays
  float* zb    = ws + S0;                           // BHW*128 f32 (z gate)
  float* qpart = ws + S0 + 1802240;                 // BHW*128 f32 (q x-part)
  bf16* rhb    = (bf16*)(ws + S0 + 3604480);        // BHW*128 bf16 (r*h)
  bf16* dm     = (bf16*)(ws + S0);                  // BHW*512 bf16 (heads)

  float* out_net  = (float*)d_out;
  float* out_mask = out_net + 1802240;
  float* out_df   = out_net + 9912320;

  dim3 blk(256);

  // --- prepack + transforms: memset then ONE init launch ---
  hipMemsetAsync(ws + 3604480, 0, (size_t)8435456, stream);
  hipMemsetAsync(out_df, 0, (size_t)28160*sizeof(float), stream);   // df atomics
  XP X{};
  const float* wl[17] = {w_cor1,w_cor2,w_flo2,w_mo,w_qk,w_v,wz1,wr1,wq1,wz2,wr2,wq2,w_f1,w_m1,w_f2,w_m2,w_flo1};
  const float* bl[15] = {b_cor1,b_cor2,b_flo2,b_mo,bz1,br1,bq1,bz2,br2,bq2,b_f1,b_m1,b_f2,b_m2,b_flo1};
  for (int i=0;i<17;++i) X.wp.w[i]=wl[i];
  for (int i=0;i<15;++i) X.bp.b[i]=bl[i];
  X.net=net; X.inp=inp; X.corr=corr; X.flow=flow;
  X.Bp=BPp; X.bias=BIASp; X.hx=hx; X.hcur=hcur; X.corr_cl=corr_cl; X.im2c=im2c;
  init_k<<<dim3(14368+880+1320+110+7040+1),blk,0,stream>>>(X);

  GP g0{};   // dummy (ntiles=0)

  // --- motion encoder (merged independent pairs) ---
  {
    GP a = mkgp(corr_cl,384, BPp+0,       BIASp+0,    fc1o,256,0,256, 384,256, 0,1,0,1.f, 2);
    GP b = mkgp(im2c,128,    BPp+4194304, BIASp+3200, ff1o,128,0,128, 128,128, 0,1,0,1.f, 1);
    gemm_conv<<<dim3(220,3),blk,0,stream>>>(a, b, g0, zp);
  }
  {
    GP a = mkgp(fc1o,256,    BPp+98304,   BIASp+256,  catB,256,0,192, 256,256, 1,1,0,1.f, 2);
    GP b = mkgp(ff1o,128,    BPp+688128,  BIASp+512,  catB,256,192,64,128,128, 1,1,0,1.f, 1);
    gemm_conv<<<dim3(220,3),blk,0,stream>>>(a, b, g0, zp);
  }

  // --- enc3 tap-split (3x12 steps, atomic f32 staging) || QK ---
  hipMemsetAsync(fc1oF, 0, (size_t)7208960, stream);    // zero staging
  {
    GP a = mkgp(catB,256,    BPp+835584,  BIASp+640,  fc1oF,128,0,126,256,128, 1,0,6,1.f, 3);
    a.tapSplit = 1; a.ntapN = 3;     // taps {0-2},{3-5},{6-8}
    GP b = mkgp(hx+128,512,  BPp+1130496, BIASp+768,  QKb, 256,0,256, 128,256, 0,0,0,1.f, 2);
    gemm_conv<<<dim3(220,5),blk,0,stream>>>(a, b, g0, zp);
  }
  merge_k<<<dim3(220),blk,0,stream>>>(fc1oF, hx);       // relu+bf16 -> hx[256:382)

  // --- V -> Vt directly (bf16 ch-major epilogue) ---
  {
    GP a = mkgp(hx+256,512,  BPp+1163264, BIASp+1024, Vt,  128,0,128, 128,128, 0,0,5,1.f, 1);
    gemm_conv<<<dim3(220,1),blk,0,stream>>>(a, g0, g0, zp);
  }
  attn_k<<<dim3(504),blk,0,stream>>>(QKb, Vt, hx, gamma, w_prelu);

  // --- GRU layer 1 (1x5): {z, r->rhb, qx->qpart} then small qh+update ---
  {
    GP a = mkgp(hx,512,      BPp+1179648, BIASp+1152, zb,  128,0,128, 512,256, 2,2,1,1.f, 1);
    GP b = mkgp(hx,512,      BPp+1179648, BIASp+1152, rhb, 0,0,256,   512,256, 2,2,3,1.f, 1);
    b.ntOff = 1; b.auxH = hcur;
    GP c = mkgp(hx+128,512,  BPp+1916928, ZB0,        qpart,128,0,128,384,128, 2,0,1,1.f, 1);
    gemm_conv<<<dim3(220,3),blk,0,stream>>>(a, b, c, zp);
  }
  {
    GP a = mkgp(rhb,128,     BPp+1835008, BIASp+1408, hx,  0,0,128,   128,128, 2,3,4,1.f, 1);
    a.auxZ = zb; a.auxH = hcur; a.auxN = nullptr; a.auxQ = qpart;
    gemm_conv<<<dim3(220,1),blk,0,stream>>>(a, g0, g0, zp);
  }

  // --- GRU layer 2 (5x1) ---
  {
    GP a = mkgp(hx,512,      BPp+2162688, BIASp+1536, zb,  128,0,128, 512,256, 3,2,1,1.f, 1);
    GP b = mkgp(hx,512,      BPp+2162688, BIASp+1536, rhb, 0,0,256,   512,256, 3,2,3,1.f, 1);
    b.ntOff = 1; b.auxH = hcur;
    GP c = mkgp(hx+128,512,  BPp+2899968, ZB0,        qpart,128,0,128,384,128, 3,0,1,1.f, 1);
    gemm_conv<<<dim3(220,3),blk,0,stream>>>(a, b, c, zp);
  }
  {
    GP a = mkgp(rhb,128,     BPp+2818048, BIASp+1792, hx,  0,0,128,   128,128, 3,3,4,1.f, 1);
    a.auxZ = zb; a.auxH = hcur; a.auxN = out_net; a.auxQ = qpart;
    gemm_conv<<<dim3(220,1),blk,0,stream>>>(a, g0, g0, zp);
  }

  // --- heads: f1 -> dm; then {mask (5 tiles) || df tap-split (3 tiles)} ---
  {
    GP a = mkgp(hx,512,      BPp+3145728, BIASp+1920, dm,  512,0,512, 128,512, 1,1,0,1.f, 4);
    gemm_conv<<<dim3(220,4),blk,0,stream>>>(a, g0, g0, zp);
  }
  {
    GP a = mkgp(dm+256,512,  BPp+4030464, BIASp+2560, out_mask,576,0,576,256,640, 0,0,2,0.25f, 5);
    GP b = mkgp(dm,512,      BPp+3735552, BIASp+2432, out_df,  2,  0,2,  256,128, 1,0,6,1.f,   3);
    b.tapSplit = 1; b.ntapN = 3;     // taps {0-2},{3-5},{6-8}; 12 steps each
    gemm_conv<<<dim3(220,8),blk,0,stream>>>(a, b, g0, zp);
  }
}

// Round 12
// 487.978 us; speedup vs baseline: 1.5394x; 1.5394x over previous
//
#include <hip/hip_runtime.h>
#include <hip/hip_bf16.h>

typedef __bf16 bf16;
typedef __attribute__((ext_vector_type(8))) __bf16 v8bf;
typedef __attribute__((ext_vector_type(4))) float f32x4;
typedef __attribute__((ext_vector_type(16))) float f32x16;

#define HH 55
#define WW 128
#define HWP 7040
#define BHW 14080
#define QS 0.08838834764831845f
#define LOG2E 1.4426950408889634f

__device__ __forceinline__ void g2l16(const bf16* g, bf16* l){
  __builtin_amdgcn_global_load_lds(
      (const __attribute__((address_space(1))) void*)g,
      (__attribute__((address_space(3))) void*)l, 16, 0, 0);
}

// ===========================================================================
// Weight prepack tables. Bp[t][co][ci] bf16 (B^T layout), zero-padded.
// Q half of w_qk pre-scaled by QS. Dst-major enumeration (coalesced writes).
// Entries 8/11: r*h-slice (K=128) of wq1/wq2; 17/18: x-slice (K=384,off 128).
// ===========================================================================
#define NCV 19
__device__ const int PK_srcCS[NCV]  = {324,256,128,256,128,128,512,512,512,512,512,512,128,128,256,256,98,512,512};
__device__ const int PK_csv[NCV]    = {324,256,128,256,128,128,512,512,128,512,512,128,128,128,256,256,98,384,384};
__device__ const int PK_srcOff[NCV] = {0,0,0,0,0,0,0,0,0,0,0,0,0,0,0,0,0,128,128};
__device__ const int PK_wsrc[NCV]   = {0,1,2,3,4,5,6,7,8,9,10,11,12,13,14,15,16,8,11};
__device__ const int PK_Kc[NCV]     = {384,256,128,256,128,128,512,512,128,512,512,128,128,128,256,256,128,384,384};
__device__ const int PK_ntap[NCV]   = {1,9,9,9,1,1,5,5,5,5,5,5,9,9,9,1,1,5,5};
__device__ const int PK_Ctot[NCV]   = {256,256,128,128,256,128,256,256,128,256,256,128,512,512,128,640,128,128,128};
__device__ const int PK_coB[NCV]    = {0,0,0,0,0,0,0,128,0,0,128,0,0,256,0,0,0,0,0};
__device__ const int PK_dst[NCV]    = {0,98304,688128,835584,1130496,1163264,1179648,1179648,
  1835008,2162688,2162688,2818048,3145728,3145728,3735552,4030464,4194304,1916928,2899968};
__device__ const int PKD_cum[NCV+1] = {0,98304,540672,614400,904704,937472,953856,
  1281536,1609216,1691136,2018816,2346496,2428416,2723328,3018240,3022848,3170304,
  3186688,3432448,3678208};
__device__ const int PKD_Co[NCV]    = {256,192,64,126,256,128,128,128,128,128,128,128,256,256,2,576,128,128,128};

__device__ const int PB_off[15]={0,256,512,640,1152,1280,1408,1536,1664,1792,1920,2176,2432,2560,3200};
__device__ const int PB_cnt[15]={256,192,64,126,128,128,128,128,128,128,256,256,2,576,128};

struct W17 { const float* w[17]; };
struct B15 { const float* b[15]; };

// ===========================================================================
// init_k: one launch for {pack_w (dst-major), transp2, transp_f(corr),
// tflow, im2col, pack_b} — all mutually independent.
// ===========================================================================
struct XP {
  W17 wp; B15 bp;
  const float *net, *inp, *corr, *flow;
  bf16 *Bp; float *bias;
  bf16 *hx; float *hcur; bf16 *corr_cl; bf16 *im2c;
};

__global__ __launch_bounds__(256) void init_k(XP X){
  __shared__ float T[64][65];
  int bid = blockIdx.x;
  const int t = threadIdx.x;
  if (bid < 14368){
    int idx = bid*256 + t;                 // 3678208 = 14368*256
    int c = 0;
    while (idx >= PKD_cum[c+1]) ++c;
    int local = idx - PKD_cum[c];
    if (c == 16){
      int co = local >> 7, k = local & 127;
      if (k < 98)
        X.Bp[PK_dst[16] + co*128 + k] = (bf16)X.wp.w[16][co*98 + (k&1)*49 + (k>>1)];
      return;
    }
    int Kc = PK_Kc[c];
    int CKc = PKD_Co[c]*Kc;
    int tap = local / CKc;
    int rem = local - tap*CKc;
    int co = rem / Kc;
    int ci = rem - co*Kc;
    if (ci < PK_csv[c]){
      float v = X.wp.w[PK_wsrc[c]][(co*PK_srcCS[c] + PK_srcOff[c] + ci)*PK_ntap[c] + tap];
      if (c == 4 && co < 128) v *= QS;     // Q half pre-scaled
      X.Bp[PK_dst[c] + (tap*PK_Ctot[c] + PK_coB[c] + co)*Kc + ci] = (bf16)v;
    }
    return;
  }
  bid -= 14368;
  if (bid < 880){                          // transp2: net/inp -> hx + hcur
    int pt = bid%110, ct = (bid/110)&3, b = bid/440;
    const float* src = (ct < 2) ? X.net : X.inp;
    int c0s = (ct & 1)*64;
    int cbase = (ct < 2) ? 0 : 128;
    int p0 = pt*64;
    int pj = t & 63, cr4 = t >> 6;
#pragma unroll
    for (int i=0;i<16;++i)
      T[cr4 + i*4][pj] = src[((size_t)b*128 + c0s + cr4 + i*4)*HWP + p0 + pj];
    __syncthreads();
    int cj = t & 63, pr4 = t >> 6;
#pragma unroll
    for (int i=0;i<16;++i){
      int pp = p0 + pr4 + i*4;
      float v = T[cj][pr4 + i*4];
      X.hx[((size_t)(b*HWP+pp))*512 + cbase + c0s + cj] = (bf16)v;
      if (ct < 2) X.hcur[((size_t)(b*HWP+pp))*128 + c0s + cj] = v;
    }
    return;
  }
  bid -= 880;
  if (bid < 1320){                         // transp_f: corr -> corr_cl (384 pad)
    int pt = bid%110, ct = (bid/110)%6, b = bid/660;
    int p0 = pt*64, c0s = ct*64;
    int pj = t & 63, cr4 = t >> 6;
#pragma unroll
    for (int i=0;i<16;++i){
      int c = c0s + cr4 + i*4;
      float v = 0.f;
      if (c < 324) v = X.corr[((size_t)b*324 + c)*HWP + p0 + pj];
      T[cr4 + i*4][pj] = v;
    }
    __syncthreads();
    int cj = t & 63, pr4 = t >> 6;
#pragma unroll
    for (int i=0;i<16;++i){
      int pp = p0 + pr4 + i*4;
      int cc = c0s + cj;
      X.corr_cl[((size_t)(b*HWP+pp))*384 + cc] = (bf16)T[cj][pr4 + i*4];
    }
    return;
  }
  bid -= 1320;
  if (bid < 110){                          // tflow: flow -> hx[382:384)
    int i = bid*256 + t;                   // BHW*2
    int c = i & 1, p = i >> 1;
    int b = p / HWP, pix = p - b*HWP;
    X.hx[(size_t)p*512 + 382 + c] = (bf16)X.flow[(b*2+c)*HWP + pix];
    return;
  }
  bid -= 110;
  if (bid < 7040){                         // im2col: flow 7x7 -> im2c
    int i = bid*256 + t;                   // BHW*128
    int k = i & 127, p = i >> 7;
    int b = p / HWP, pix = p - b*HWP, y = pix >> 7, x = pix & 127;
    float v = 0.f;
    if (k < 98){
      int tap = k >> 1, c2 = k & 1, kh = tap/7, kw = tap - 7*(tap/7);
      int yy = y + kh - 3, xx = x + kw - 3;
      if ((unsigned)yy < 55u && (unsigned)xx < 128u) v = X.flow[(b*2+c2)*HWP + yy*128 + xx];
    }
    X.im2c[i] = (bf16)v;
    return;
  }
  // pack_b (last block)
  for (int e=0;e<15;++e)
    for (int o=t; o<PB_cnt[e]; o+=256)
      X.bias[PB_off[e]+o] = X.bp.b[e][o];
}

// ===========================================================================
// Implicit-GEMM conv: M64 x N128, BK=64, 4 waves 2x2. Triple-param launch.
// tapSplit tiles: nt selects a tap-range (tOff = nt*ntapN) with shared N
// range; partials atomically accumulated (outmode 6 — ONLY valid for tiny
// Nvalid; full-width atomic accumulation measured catastrophic in r11).
// Epilogue outmodes: 0 bf16 pix-major; 2 f32 ch-major; 5 bf16 ch-major (Vt);
// 6 f32 ch-major atomicAdd (df head, Nvalid=2); 1/3/4 scalar (GRU fusion;
// auxQ adds q x-part before activation).
// ===========================================================================
struct GP {
  const bf16* A; const bf16* A2;
  const bf16* Bp; const float* bias;
  void* outp; const float* auxZ; float* auxH; float* auxN; const float* auxQ;
  int Astride, A2stride, Asplit;
  int outCtot, outC0, Nvalid, Kc, CtotPad, tapcode, act, outmode, ntiles, ntOff;
  int ntapN, tapSplit;
  float scale;
};

__global__ __launch_bounds__(256) void gemm_conv(GP ga, GP gb, GP gc, const bf16* __restrict__ zp)
{
  const int Mt = blockIdx.x;            // 0..219
  int nt = blockIdx.y;
  GP g;
  if (nt < ga.ntiles){ g = ga; }
  else if (nt < ga.ntiles + gb.ntiles){ g = gb; nt -= ga.ntiles; }
  else { g = gc; nt -= ga.ntiles + gb.ntiles; }
  int tOff = 0;
  if (g.tapSplit){ tOff = nt * g.ntapN; nt = 0; }
  const bf16* A        = g.A;
  const bf16* A2       = g.A2;
  const bf16* Bp       = g.Bp;
  const float* bias    = g.bias;
  void* outp           = g.outp;
  const float* auxZ    = g.auxZ;
  float* auxH          = g.auxH;
  float* auxN          = g.auxN;
  const float* auxQ    = g.auxQ;
  const int Astride    = g.Astride;
  const int A2stride   = g.A2stride;
  const int Asplit     = g.Asplit;
  const int outCtot    = g.outCtot;
  const int outC0      = g.outC0;
  const int Nvalid     = g.Nvalid;
  const int Kc         = g.Kc;
  const int CtotPad    = g.CtotPad;
  const int tapcode    = g.tapcode;
  const int act        = g.act;
  const int outmode    = g.outmode;
  const int ntOff      = g.ntOff;
  const float scale    = g.scale;

  const int bimg = Mt/110;
  const int rem = Mt - bimg*110;
  const int yy0 = rem >> 1;
  const int xh  = (rem & 1) << 6;
  const int tid = threadIdx.x;
  const int lane = tid & 63, wave = tid >> 6;
  const int wm = wave >> 1, wn = wave & 1;
  const int lr = lane & 15, lq2 = lane >> 4;

  __shared__ __align__(16) bf16 Al[2][4096];   // [buf][64 rows x 64 elems]
  __shared__ __align__(16) bf16 Bl[2][8192];   // [buf][128 rows x 64 elems]

  f32x4 acc[2][4];
#pragma unroll
  for (int m=0;m<2;++m)
#pragma unroll
    for (int n=0;n<4;++n) acc[m][n] = (f32x4){0.f,0.f,0.f,0.f};

  const int ntap = g.ntapN ? g.ntapN : ((tapcode==0) ? 1 : (tapcode==1 ? 9 : 5));
  const int nsteps = ntap*(Kc>>6);

  const int srow = tid >> 3;            // 0..31
  const int sc   = tid & 7;             // chunk 0..7

#define STAGE(BUF, T, KC) { \
    int TT = (T) + tOff; \
    int ddy, ddx; \
    if (tapcode==0){ ddy=0; ddx=0; } \
    else if (tapcode==1){ ddy=TT/3-1; ddx=TT-3*(TT/3)-1; } \
    else if (tapcode==2){ ddy=0; ddx=TT-2; } \
    else { ddy=TT-2; ddx=0; } \
    int ysrc = yy0 + ddy; \
    bool yok = (unsigned)ysrc < 55u; \
    const bf16* Abase; int Astr; \
    if ((KC) < Asplit){ Astr = A2stride; \
      Abase = A2 + (size_t)((bimg*55+ysrc)*128)*Astr + (KC); } \
    else { Astr = Astride; \
      Abase = A + (size_t)((bimg*55+ysrc)*128)*Astr + (KC); } \
    _Pragma("unroll") \
    for (int is=0; is<2; ++is){ \
      int r = is*32 + srow; \
      int cc = sc ^ (r&7); \
      int gx = xh + r + ddx; \
      const bf16* srcp = (yok && (unsigned)gx < 128u) ? \
          (Abase + (size_t)gx*Astr + cc*8) : (zp + cc*8); \
      g2l16(srcp, &Al[BUF][is*2048 + wave*512]); \
    } \
    const bf16* Bt = Bp + (size_t)(TT*CtotPad + (nt+ntOff)*128)*Kc + (KC); \
    _Pragma("unroll") \
    for (int is=0; is<4; ++is){ \
      int r = is*32 + srow; \
      int cc = sc ^ (r&7); \
      g2l16(Bt + (size_t)r*Kc + cc*8, &Bl[BUF][is*2048 + wave*512]); \
    } }

  STAGE(0, 0, 0);
  __syncthreads();

  int tcur = 0, kcc = 0;
  for (int si=0; si<nsteps; ++si){
    int kn = kcc + 64, tn = tcur;
    if (kn == Kc){ kn = 0; tn = tcur + 1; }
    if (si + 1 < nsteps){ STAGE((si+1)&1, tn, kn); }
    __builtin_amdgcn_sched_barrier(0);
    kcc = kn; tcur = tn;
    const bf16* Ac = Al[si&1];
    const bf16* Bc = Bl[si&1];
#pragma unroll
    for (int kk=0; kk<2; ++kk){
      v8bf af[2], bfr[4];
#pragma unroll
      for (int m=0;m<2;++m){
        int row = wm*32 + m*16 + lr;
        af[m] = *(const v8bf*)(Ac + row*64 + (((kk*4+lq2) ^ (row&7))<<3));
      }
#pragma unroll
      for (int n=0;n<4;++n){
        int row = wn*64 + n*16 + lr;
        bfr[n] = *(const v8bf*)(Bc + row*64 + (((kk*4+lq2) ^ (row&7))<<3));
      }
#pragma unroll
      for (int m=0;m<2;++m)
#pragma unroll
        for (int n=0;n<4;++n)
          acc[m][n] = __builtin_amdgcn_mfma_f32_16x16x32_bf16(af[m], bfr[n], acc[m][n], 0,0,0);
    }
    __syncthreads();
  }
#undef STAGE

  const size_t pixbase = (size_t)(bimg*55 + yy0)*128 + xh;
  if (outmode == 0){
    // bf16 pix-major: LDS transpose (XOR-chunk swizzle) -> uint4 stores.
    bf16* Ost = (bf16*)Al;              // 64 x 128 bf16 = 16KB
#pragma unroll
    for (int nn=0; nn<4; ++nn){
      int colL = wn*64 + nn*16 + lr;
      float bvl = bias[(nt+ntOff)*128 + colL];
#pragma unroll
      for (int m=0;m<2;++m){
        int rowx = wm*32 + m*16 + lq2*4;
        f32x4 v = acc[m][nn];
#pragma unroll
        for (int r=0;r<4;++r){
          float vv = v[r] + bvl;
          if (act==1)      vv = fmaxf(vv, 0.f);
          else if (act==2) vv = 1.f/(1.f+__expf(-vv));
          else if (act==3) vv = tanhf(vv);
          vv *= scale;
          int row = rowx + r;
          int pch = (colL>>3) ^ (row & 7);
          Ost[row*128 + (pch<<3) + (colL&7)] = (bf16)vv;
        }
      }
    }
    __syncthreads();
    {
      int rowl = tid >> 2, seg = tid & 3;
      size_t p = pixbase + rowl;
      bf16* dstp = (bf16*)outp + p*outCtot + outC0 + (nt+ntOff)*128 + seg*32;
      const bf16* srcr = Ost + rowl*128;
      int cb = (nt+ntOff)*128 + seg*32;
#pragma unroll
      for (int k2=0;k2<4;++k2){
        int pch = (seg*4 + k2) ^ (rowl & 7);
        int cog = cb + k2*8;
        if (cog + 8 <= Nvalid)
          *(uint4*)(dstp + k2*8) = *(const uint4*)(srcr + (pch<<3));
        else if (cog < Nvalid){
          const bf16* s8 = srcr + (pch<<3);
          for (int e=0; e<Nvalid-cog; ++e) dstp[k2*8+e] = s8[e];
        }
      }
    }
  } else if (outmode == 2 || outmode == 6){
    // f32 channel-major: LDS [ch][row] -> 16B stores (2) or atomicAdd (6).
    float* Ost2 = (float*)Bl;           // 128 ch x 64 row f32 = 32KB
#pragma unroll
    for (int nn=0; nn<4; ++nn){
      int chL = wn*64 + nn*16 + lr;
      float bvl = (outmode==6 && tOff!=0) ? 0.f : bias[(nt+ntOff)*128 + chL];
#pragma unroll
      for (int m=0;m<2;++m){
        int rowx = wm*32 + m*16 + lq2*4;
        f32x4 v = acc[m][nn];
#pragma unroll
        for (int r=0;r<4;++r){
          float vv = v[r] + bvl;
          if (act==1)      vv = fmaxf(vv, 0.f);
          else if (act==2) vv = 1.f/(1.f+__expf(-vv));
          else if (act==3) vv = tanhf(vv);
          Ost2[chL*64 + rowx + r] = vv*scale;
        }
      }
    }
    __syncthreads();
    {
      int ch = tid >> 1, half = tid & 1;
      int cog = (nt+ntOff)*128 + ch;
      if (cog < Nvalid){
        float* dstp = (float*)outp + ((size_t)bimg*outCtot + outC0 + cog)*HWP
                    + yy0*128 + xh + half*32;
        const float* srcr = Ost2 + ch*64 + half*32;
        if (outmode == 2){
#pragma unroll
          for (int k2=0;k2<8;++k2)
            *(uint4*)(dstp + k2*4) = *(const uint4*)(srcr + k2*4);
        } else {
#pragma unroll
          for (int e=0;e<32;++e)
            atomicAdd(dstp + e, srcr[e]);
        }
      }
    }
  } else if (outmode == 5){
    // bf16 channel-major (Vt direct): LDS [ch][72pad] -> 16B stores along pix.
    bf16* Ost3 = (bf16*)Bl;             // 128 ch x 72 bf16 = 18.4KB (pad->align)
#pragma unroll
    for (int nn=0; nn<4; ++nn){
      int chL = wn*64 + nn*16 + lr;
      float bvl = bias[(nt+ntOff)*128 + chL];
#pragma unroll
      for (int m=0;m<2;++m){
        int rowx = wm*32 + m*16 + lq2*4;
        f32x4 v = acc[m][nn];
#pragma unroll
        for (int r=0;r<4;++r)
          Ost3[chL*72 + rowx + r] = (bf16)(v[r] + bvl);
      }
    }
    __syncthreads();
    {
      int ch = tid >> 1, half = tid & 1;
      bf16* dstp = (bf16*)outp + ((size_t)bimg*outCtot + outC0 + ch)*HWP
                 + yy0*128 + xh + half*32;
      const bf16* srcr = Ost3 + ch*72 + half*32;
#pragma unroll
      for (int k2=0;k2<4;++k2)
        *(uint4*)(dstp + k2*8) = *(const uint4*)(srcr + k2*8);
    }
  } else {
#pragma unroll
    for (int nn=0; nn<4; ++nn){
      int cog = (nt+ntOff)*128 + wn*64 + nn*16 + lr;
      float bvl = bias[cog];
      bool cok = cog < Nvalid;
#pragma unroll
      for (int m=0;m<2;++m){
        int rowx = wm*32 + m*16 + lq2*4;
        f32x4 v = acc[m][nn];
#pragma unroll
        for (int r=0;r<4;++r){
          int prow = rowx + r;
          size_t p = pixbase + prow;
          float vv = v[r] + bvl;
          if (outmode==4 && auxQ) vv += auxQ[p*128 + cog];
          if (act==1)      vv = fmaxf(vv, 0.f);
          else if (act==2) vv = 1.f/(1.f+__expf(-vv));
          else if (act==3) vv = tanhf(vv);
          vv *= scale;
          if (cok){
            if (outmode==1) ((float*)outp)[p*outCtot + outC0 + cog] = vv;
            else if (outmode==3){               // r-gate: rhb = sigmoid(.)*hcur
              int c = cog & 127;
              ((bf16*)outp)[p*128 + c] = (bf16)(vv * auxH[p*128 + c]);
            } else {                            // outmode==4: GRU update
              int c = cog;
              float z  = auxZ[p*128 + c];
              float h0 = auxH[p*128 + c];
              float hn = (1.f - z)*h0 + z*vv;
              auxH[p*128 + c] = hn;
              ((bf16*)outp)[p*512 + c] = (bf16)hn;
              if (auxN){
                int pixloc = (int)(p - (size_t)bimg*HWP);
                auxN[((size_t)bimg*128 + c)*HWP + pixloc] = hn;
              }
            }
          }
        }
      }
    }
  }
}

// ===========================================================================
// MFMA flash attention. r7 in-loop body (empirical best ~84us): single
// 8-deep QK chain, serial fmax, serial den, T12 cvt_pk+permlane pack,
// vectorized RMW epilogue. In-loop reorders measured harmful (r4/r8).
// ===========================================================================
__global__ __launch_bounds__(256,1) void attn_k(
    const bf16* __restrict__ QK, const bf16* __restrict__ Vt,
    bf16* __restrict__ hx,
    const float* __restrict__ gammap, const float* __restrict__ wprelup)
{
  __shared__ __align__(16) float SM[16640];
  const int tid = threadIdx.x;
  const int wv = tid >> 6, lane = tid & 63;
  const int lq = lane & 31, hi = lane >> 5;
  const int blk = blockIdx.x;
  const int qt = blk % 12;
  const int n  = (blk/12) % 21;
  const int b  = blk / 252;
  const int hs = n/7, wd = n - 7*hs;
  const int y0 = (hs-1)*19, x0 = (wd-1)*19;
  const int rylo = max(0, y0), ryhi = min(54, y0+56);
  const int rxlo = max(0, x0), rxhi = min(127, x0+56);
  const int rxA  = rxlo & ~7;
  const int s = qt*32 + lq;
  const int sy = s/19, sx = s - sy*19;
  const int qy = y0 + 19 + sy, qx = x0 + 19 + sx;
  const int qpix = (b*55 + min(qy,54))*128 + min(qx,127);
  const float a = wprelup[0]*0.02f;
  const float qyf = (float)qy;

  bf16* Kl = (bf16*)SM + wv*8192;
  bf16* Vl = Kl + 4096;

  v8bf qf[8];
#pragma unroll
  for (int ks=0; ks<8; ++ks)
    qf[ks] = *(const v8bf*)(QK + (size_t)qpix*256 + ks*16 + hi*8);

  float fx0[16], fx1[16];
  unsigned msk0 = 0, msk1 = 0;
  {
    float dxq0 = (float)(rxA - qx);
    int xl0 = rxlo - rxA, xm0 = rxhi - rxA;
#pragma unroll
    for (int r=0;r<16;++r){
      int Ri = (r&3) + 8*(r>>2) + 4*hi;
      float dxv = fabsf(dxq0 + (float)Ri) - 38.f;
      fx0[r] = fmaxf(1.f - fmaxf(dxv, a*dxv), 0.f);
      if (Ri >= xl0 && Ri <= xm0) msk0 |= 1u<<r;
      float dxv1 = fabsf(dxq0 + 32.f + (float)Ri) - 38.f;
      fx1[r] = fmaxf(1.f - fmaxf(dxv1, a*dxv1), 0.f);
      int Ri1 = Ri + 32;
      if (Ri1 >= xl0 && Ri1 <= xm0) msk1 |= 1u<<r;
    }
  }

  f32x16 acc[4];
#pragma unroll
  for (int nf=0; nf<4; ++nf)
#pragma unroll
    for (int r=0;r<16;++r) acc[nf][r] = 0.f;
  float m2 = -40.f, den = 0.f;

  const int nry = (ryhi - rylo - wv)/4 + 1;   // >= 9
  const int nit = nry*2;

#define ISSUE_K(RY, RX) { int pixK = (b*55+(RY))*128 + (RX); \
  _Pragma("unroll") \
  for (int i=0;i<8;++i){ \
    int key = i*4 + (lane>>4); int cs = (lane&15) ^ (key&7); \
    g2l16(QK + (size_t)(pixK+key)*256 + 128 + cs*8, Kl + i*512); } }
#define ISSUE_V(RY, RX) { \
  _Pragma("unroll") \
  for (int i=0;i<8;++i){ \
    int ch = i*16 + (lane>>2); int cs = (lane&3) ^ ((ch>>1)&3); \
    g2l16(Vt + (size_t)(b*128+ch)*HWP + (RY)*128 + (RX) + cs*8, Vl + i*512); } }

  ISSUE_K(rylo + wv, rxA);

  for (int it=0; it<nit; ++it){
    const int ry  = rylo + wv + (it>>1)*4;
    const int tpar = it & 1;
    asm volatile("s_waitcnt lgkmcnt(0)" ::: "memory");
    __builtin_amdgcn_sched_barrier(0);
    asm volatile("s_waitcnt vmcnt(0)" ::: "memory");
    __builtin_amdgcn_sched_barrier(0);
    ISSUE_V(ry, rxA + tpar*32);
    __builtin_amdgcn_sched_barrier(0);

    f32x16 Cs;
#pragma unroll
    for (int r=0;r<16;++r) Cs[r] = 0.f;
#pragma unroll
    for (int ks=0; ks<8; ++ks){
      v8bf kf = *(const v8bf*)(Kl + lq*128 + (((ks*2+hi) ^ (lq&7))<<3));
      Cs = __builtin_amdgcn_mfma_f32_32x32x16_bf16(kf, qf[ks], Cs, 0,0,0);
    }
    float pr[16];
    {
      float dyv = fabsf((float)ry - qyf) - 38.f;
      float fy = fmaxf(1.f - fmaxf(dyv, a*dyv), 0.f);
      float fyk = fy * LOG2E;
      unsigned mk = tpar ? msk1 : msk0;
      float l2v[16]; float tmax = -1e30f;
#pragma unroll
      for (int r=0;r<16;++r){
        float fx = tpar ? fx1[r] : fx0[r];
        float lv = fyk * fx * Cs[r];
        lv = ((mk>>r)&1u) ? lv : -1e30f;
        l2v[r] = lv;
        tmax = fmaxf(tmax, lv);
      }
      tmax = fmaxf(tmax, __shfl_xor(tmax, 32));
      if (__any(tmax > m2 + 11.f)){
        float m2n = fmaxf(m2, tmax);
        float sc = exp2f(m2 - m2n);
        den *= sc;
#pragma unroll
        for (int r=0;r<16;++r){
          float scr = __shfl(sc, (r&3) + 8*(r>>2) + 4*hi);
          acc[0][r]*=scr; acc[1][r]*=scr; acc[2][r]*=scr; acc[3][r]*=scr;
        }
        m2 = m2n;
      }
#pragma unroll
      for (int r=0;r<16;++r){
        pr[r] = exp2f(l2v[r] - m2);
        den += pr[r];
      }
    }
    asm volatile("s_waitcnt lgkmcnt(0)" ::: "memory");
    __builtin_amdgcn_sched_barrier(0);
    asm volatile("s_waitcnt vmcnt(0)" ::: "memory");
    __builtin_amdgcn_sched_barrier(0);
    if (it + 1 < nit){
      int ryn = rylo + wv + ((it+1)>>1)*4;
      ISSUE_K(ryn, rxA + ((it+1)&1)*32);
      __builtin_amdgcn_sched_barrier(0);
    }
    // T12 pack: 8 cvt_pk + 4 permlane32_swap -> pa0/pa1 directly.
    unsigned w0,w1,w2,w3,w4,w5,w6,w7;
    asm("v_cvt_pk_bf16_f32 %0, %1, %2" : "=v"(w0) : "v"(pr[0]),  "v"(pr[1]));
    asm("v_cvt_pk_bf16_f32 %0, %1, %2" : "=v"(w1) : "v"(pr[2]),  "v"(pr[3]));
    asm("v_cvt_pk_bf16_f32 %0, %1, %2" : "=v"(w2) : "v"(pr[4]),  "v"(pr[5]));
    asm("v_cvt_pk_bf16_f32 %0, %1, %2" : "=v"(w3) : "v"(pr[6]),  "v"(pr[7]));
    asm("v_cvt_pk_bf16_f32 %0, %1, %2" : "=v"(w4) : "v"(pr[8]),  "v"(pr[9]));
    asm("v_cvt_pk_bf16_f32 %0, %1, %2" : "=v"(w5) : "v"(pr[10]), "v"(pr[11]));
    asm("v_cvt_pk_bf16_f32 %0, %1, %2" : "=v"(w6) : "v"(pr[12]), "v"(pr[13]));
    asm("v_cvt_pk_bf16_f32 %0, %1, %2" : "=v"(w7) : "v"(pr[14]), "v"(pr[15]));
    asm("v_permlane32_swap_b32 %0, %1" : "+v"(w0), "+v"(w2));
    asm("v_permlane32_swap_b32 %0, %1" : "+v"(w1), "+v"(w3));
    asm("v_permlane32_swap_b32 %0, %1" : "+v"(w4), "+v"(w6));
    asm("v_permlane32_swap_b32 %0, %1" : "+v"(w5), "+v"(w7));
    union { unsigned u[4]; v8bf v; } U0, U1;
    U0.u[0]=w0; U0.u[1]=w1; U0.u[2]=w2; U0.u[3]=w3;
    U1.u[0]=w4; U1.u[1]=w5; U1.u[2]=w6; U1.u[3]=w7;
    v8bf pa0 = U0.v, pa1 = U1.v;
#pragma unroll
    for (int nf=0; nf<4; ++nf){
      int ch = nf*32 + lq;
      int sw = (lq>>1)&3;
      v8bf v0 = *(const v8bf*)(Vl + ch*32 + ((hi     ^ sw)<<3));
      v8bf v1 = *(const v8bf*)(Vl + ch*32 + (((2+hi) ^ sw)<<3));
      acc[nf] = __builtin_amdgcn_mfma_f32_32x32x16_bf16(pa0, v0, acc[nf], 0,0,0);
      acc[nf] = __builtin_amdgcn_mfma_f32_32x32x16_bf16(pa1, v1, acc[nf], 0,0,0);
    }
  }
#undef ISSUE_K
#undef ISSUE_V
  den += __shfl_xor(den, 32);

  float* Osh = SM;                    // [4][32][128]
  float* Msh = SM + 16384;
  float* Dsh = SM + 16512;
  __syncthreads();
#pragma unroll
  for (int nf=0; nf<4; ++nf)
#pragma unroll
    for (int r=0;r<16;++r)
      Osh[(wv*32 + (r&3) + 8*(r>>2) + 4*hi)*128 + nf*32 + lq] = acc[nf][r];
  if (hi == 0){ Msh[wv*32 + lq] = m2; Dsh[wv*32 + lq] = den; }
  __syncthreads();

  int q = tid >> 3, co = (tid & 7)*16;
  float m0 = Msh[q], m1 = Msh[32+q], mm2 = Msh[64+q], m3 = Msh[96+q];
  float M = fmaxf(fmaxf(m0,m1), fmaxf(mm2,m3));
  float s0 = exp2f(m0-M), s1 = exp2f(m1-M), s2 = exp2f(mm2-M), s3 = exp2f(m3-M);
  int ss = qt*32 + q;
  float dent = s0*Dsh[q] + s1*Dsh[32+q] + s2*Dsh[64+q] + s3*Dsh[96+q];
  int sy2 = ss/19, sx2 = ss - sy2*19;
  int qy2 = y0 + 19 + sy2, qx2 = x0 + 19 + sx2;
  if (ss < 361 && qy2 < 55 && qx2 < 128){
    size_t pix = (size_t)(b*55+qy2)*128 + qx2;
    float g = gammap[0] / dent;
    v8bf fm0 = *(const v8bf*)(hx + pix*512 + 256 + co);
    v8bf fm1 = *(const v8bf*)(hx + pix*512 + 256 + co + 8);
    v8bf o0, o1;
#pragma unroll
    for (int c=0;c<8;++c){
      float oa = s0*Osh[q*128+co+c] + s1*Osh[(32+q)*128+co+c]
               + s2*Osh[(64+q)*128+co+c] + s3*Osh[(96+q)*128+co+c];
      o0[c] = (bf16)((float)fm0[c] + oa*g);
      float ob = s0*Osh[q*128+co+8+c] + s1*Osh[(32+q)*128+co+8+c]
               + s2*Osh[(64+q)*128+co+8+c] + s3*Osh[(96+q)*128+co+8+c];
      o1[c] = (bf16)((float)fm1[c] + ob*g);
    }
    *(v8bf*)(hx + pix*512 + 384 + co)     = o0;
    *(v8bf*)(hx + pix*512 + 384 + co + 8) = o1;
  }
}

// ===========================================================================
static inline GP mkgp(const bf16* A, int Astride, const bf16* Bp, const float* bias,
                      void* outp, int outCtot, int outC0, int Nvalid, int Kc, int CtotPad,
                      int tapcode, int act, int outmode, float scale, int ntiles){
  GP g{};
  g.A=A; g.A2=A; g.Astride=Astride; g.A2stride=Astride; g.Asplit=0;
  g.Bp=Bp; g.bias=bias; g.outp=outp;
  g.auxZ=nullptr; g.auxH=nullptr; g.auxN=nullptr; g.auxQ=nullptr;
  g.outCtot=outCtot; g.outC0=outC0; g.Nvalid=Nvalid; g.Kc=Kc; g.CtotPad=CtotPad;
  g.tapcode=tapcode; g.act=act; g.outmode=outmode; g.ntiles=ntiles; g.ntOff=0;
  g.ntapN=0; g.tapSplit=0;
  g.scale=scale;
  return g;
}

extern "C" void kernel_launch(void* const* d_in, const int* in_sizes, int n_in,
                              void* d_out, int out_size, void* d_ws, size_t ws_size,
                              hipStream_t stream) {
  const float* net   = (const float*)d_in[0];
  const float* inp   = (const float*)d_in[1];
  const float* corr  = (const float*)d_in[2];
  const float* flow  = (const float*)d_in[3];
  const float* w_cor1=(const float*)d_in[4];  const float* b_cor1=(const float*)d_in[5];
  const float* w_cor2=(const float*)d_in[6];  const float* b_cor2=(const float*)d_in[7];
  const float* w_flo1=(const float*)d_in[8];  const float* b_flo1=(const float*)d_in[9];
  const float* w_flo2=(const float*)d_in[10]; const float* b_flo2=(const float*)d_in[11];
  const float* w_mo  =(const float*)d_in[12]; const float* b_mo  =(const float*)d_in[13];
  const float* w_qk  =(const float*)d_in[14];
  const float* w_v   =(const float*)d_in[15];
  const float* wz1=(const float*)d_in[16]; const float* bz1=(const float*)d_in[17];
  const float* wr1=(const float*)d_in[18]; const float* br1=(const float*)d_in[19];
  const float* wq1=(const float*)d_in[20]; const float* bq1=(const float*)d_in[21];
  const float* wz2=(const float*)d_in[22]; const float* bz2=(const float*)d_in[23];
  const float* wr2=(const float*)d_in[24]; const float* br2=(const float*)d_in[25];
  const float* wq2=(const float*)d_in[26]; const float* bq2=(const float*)d_in[27];
  const float* w_f1=(const float*)d_in[28]; const float* b_f1=(const float*)d_in[29];
  const float* w_f2=(const float*)d_in[30]; const float* b_f2=(const float*)d_in[31];
  const float* w_m1=(const float*)d_in[32]; const float* b_m1=(const float*)d_in[33];
  const float* w_m2=(const float*)d_in[34]; const float* b_m2=(const float*)d_in[35];
  const float* gamma  =(const float*)d_in[36];
  const float* w_prelu=(const float*)d_in[37];

  float* ws = (float*)d_ws;
  bf16* hx     = (bf16*)ws;                         // [0, 3604480)
  bf16* BPp    = (bf16*)(ws + 3604480);             // 4210688 bf16
  float* BIASp = ws + 5709824;                      // 3328 f32
  const bf16* zp = (const bf16*)(ws + 5713152);     // 256B zero page
  float* ZB0   = ws + 5713216;                      // 128 f32 zero bias
  const size_t S0 = 5713344;
  // encoder phase
  bf16* corr_cl = (bf16*)(ws + S0);                 // BHW*384 bf16
  bf16* fc1o    = (bf16*)(ws + S0 + 2703360);       // BHW*256 bf16
  bf16* catB    = (bf16*)(ws + S0 + 4505600);       // BHW*256 bf16
  bf16* ff1o    = (bf16*)(ws + S0 + 6307840);       // BHW*128 bf16
  bf16* im2c    = (bf16*)(ws + S0 + 7208960);       // BHW*128 bf16
  float* hcur   = ws + S0 + 8110080;                // BHW*128 f32
  // attention phase overlays
  bf16* QKb    = (bf16*)(ws + S0);                  // 14144*256 bf16
  bf16* Vt     = (bf16*)(ws + S0 + 2711552);        // 2*128*7040 + pad
  // GRU phase overlays
  float* zb    = ws + S0;                           // BHW*128 f32 (z gate)
  float* qpart = ws + S0 + 1802240;                 // BHW*128 f32 (q x-part)
  bf16* rhb    = (bf16*)(ws + S0 + 3604480);        // BHW*128 bf16 (r*h)
  bf16* dm     = (bf16*)(ws + S0);                  // BHW*512 bf16 (heads)

  float* out_net  = (float*)d_out;
  float* out_mask = out_net + 1802240;
  float* out_df   = out_net + 9912320;

  dim3 blk(256);

  // --- prepack + transforms: memset then ONE init launch ---
  hipMemsetAsync(ws + 3604480, 0, (size_t)8435456, stream);
  hipMemsetAsync(out_df, 0, (size_t)28160*sizeof(float), stream);   // df atomics
  XP X{};
  const float* wl[17] = {w_cor1,w_cor2,w_flo2,w_mo,w_qk,w_v,wz1,wr1,wq1,wz2,wr2,wq2,w_f1,w_m1,w_f2,w_m2,w_flo1};
  const float* bl[15] = {b_cor1,b_cor2,b_flo2,b_mo,bz1,br1,bq1,bz2,br2,bq2,b_f1,b_m1,b_f2,b_m2,b_flo1};
  for (int i=0;i<17;++i) X.wp.w[i]=wl[i];
  for (int i=0;i<15;++i) X.bp.b[i]=bl[i];
  X.net=net; X.inp=inp; X.corr=corr; X.flow=flow;
  X.Bp=BPp; X.bias=BIASp; X.hx=hx; X.hcur=hcur; X.corr_cl=corr_cl; X.im2c=im2c;
  init_k<<<dim3(14368+880+1320+110+7040+1),blk,0,stream>>>(X);

  GP g0{};   // dummy (ntiles=0)

  // --- motion encoder (merged independent pairs) ---
  {
    GP a = mkgp(corr_cl,384, BPp+0,       BIASp+0,    fc1o,256,0,256, 384,256, 0,1,0,1.f, 2);
    GP b = mkgp(im2c,128,    BPp+4194304, BIASp+3200, ff1o,128,0,128, 128,128, 0,1,0,1.f, 1);
    gemm_conv<<<dim3(220,3),blk,0,stream>>>(a, b, g0, zp);
  }
  {
    GP a = mkgp(fc1o,256,    BPp+98304,   BIASp+256,  catB,256,0,192, 256,256, 1,1,0,1.f, 2);
    GP b = mkgp(ff1o,128,    BPp+688128,  BIASp+512,  catB,256,192,64,128,128, 1,1,0,1.f, 1);
    gemm_conv<<<dim3(220,3),blk,0,stream>>>(a, b, g0, zp);
  }

  // --- enc3 (feat_mo) merged with QK (QK reads hx[128:256) only) ---
  {
    GP a = mkgp(catB,256,    BPp+835584,  BIASp+640,  hx,  512,256,126,256,128, 1,1,0,1.f, 1);
    GP b = mkgp(hx+128,512,  BPp+1130496, BIASp+768,  QKb, 256,0,256, 128,256, 0,0,0,1.f, 2);
    gemm_conv<<<dim3(220,3),blk,0,stream>>>(a, b, g0, zp);
  }
  // --- V -> Vt directly (bf16 ch-major epilogue) ---
  {
    GP a = mkgp(hx+256,512,  BPp+1163264, BIASp+1024, Vt,  128,0,128, 128,128, 0,0,5,1.f, 1);
    gemm_conv<<<dim3(220,1),blk,0,stream>>>(a, g0, g0, zp);
  }
  attn_k<<<dim3(504),blk,0,stream>>>(QKb, Vt, hx, gamma, w_prelu);

  // --- GRU layer 1 (1x5): {z, r->rhb, qx->qpart} then small qh+update ---
  {
    GP a = mkgp(hx,512,      BPp+1179648, BIASp+1152, zb,  128,0,128, 512,256, 2,2,1,1.f, 1);
    GP b = mkgp(hx,512,      BPp+1179648, BIASp+1152, rhb, 0,0,256,   512,256, 2,2,3,1.f, 1);
    b.ntOff = 1; b.auxH = hcur;
    GP c = mkgp(hx+128,512,  BPp+1916928, ZB0,        qpart,128,0,128,384,128, 2,0,1,1.f, 1);
    gemm_conv<<<dim3(220,3),blk,0,stream>>>(a, b, c, zp);
  }
  {
    GP a = mkgp(rhb,128,     BPp+1835008, BIASp+1408, hx,  0,0,128,   128,128, 2,3,4,1.f, 1);
    a.auxZ = zb; a.auxH = hcur; a.auxN = nullptr; a.auxQ = qpart;
    gemm_conv<<<dim3(220,1),blk,0,stream>>>(a, g0, g0, zp);
  }

  // --- GRU layer 2 (5x1) ---
  {
    GP a = mkgp(hx,512,      BPp+2162688, BIASp+1536, zb,  128,0,128, 512,256, 3,2,1,1.f, 1);
    GP b = mkgp(hx,512,      BPp+2162688, BIASp+1536, rhb, 0,0,256,   512,256, 3,2,3,1.f, 1);
    b.ntOff = 1; b.auxH = hcur;
    GP c = mkgp(hx+128,512,  BPp+2899968, ZB0,        qpart,128,0,128,384,128, 3,0,1,1.f, 1);
    gemm_conv<<<dim3(220,3),blk,0,stream>>>(a, b, c, zp);
  }
  {
    GP a = mkgp(rhb,128,     BPp+2818048, BIASp+1792, hx,  0,0,128,   128,128, 3,3,4,1.f, 1);
    a.auxZ = zb; a.auxH = hcur; a.auxN = out_net; a.auxQ = qpart;
    gemm_conv<<<dim3(220,1),blk,0,stream>>>(a, g0, g0, zp);
  }

  // --- heads: f1 -> dm; then {mask (5 tiles) || df tap-split (3 tiles)} ---
  {
    GP a = mkgp(hx,512,      BPp+3145728, BIASp+1920, dm,  512,0,512, 128,512, 1,1,0,1.f, 4);
    gemm_conv<<<dim3(220,4),blk,0,stream>>>(a, g0, g0, zp);
  }
  {
    GP a = mkgp(dm+256,512,  BPp+4030464, BIASp+2560, out_mask,576,0,576,256,640, 0,0,2,0.25f, 5);
    GP b = mkgp(dm,512,      BPp+3735552, BIASp+2432, out_df,  2,  0,2,  256,128, 1,0,6,1.f,   3);
    b.tapSplit = 1; b.ntapN = 3;     // taps {0-2},{3-5},{6-8}; 12 steps each
    gemm_conv<<<dim3(220,8),blk,0,stream>>>(a, b, g0, zp);
  }
}